// Round 15
// baseline (2355.500 us; speedup 1.0000x reference)
//
#include <hip/hip_runtime.h>
#include <math.h>

// L2ClusterCentroid: N=1e6 rows, D=128, C=100.
// assign = argmax(logits, -1); centroids = segment_mean(embedding, assign);
// out[c] = counts[c]>0 ? ||centers[c] - centroids[c]||_2 : 0
//
// Round-15: K1 (~90us) and K2 (~85us) are each near their pattern limits but
// serialize, wasting BW (combined floor ~145us). This round fuses them into
// one kernel with a PULL-based global ticket queue: per slice (25 slices),
// 625 argmax-group tickets then 100 gather tickets gated on a per-slice
// done-counter (release: stores->threadfence->atomicAdd; acquire spin).
// Pull-based => deadlock-immune regardless of residency (gather waves wait
// only on p1 tickets already pulled by other waves; p1 is never gated).
// Gather is per-wave (no cross-wave reduce); output bits are independent of
// wave->ticket mapping (each (c,s) partial = one wave, fixed row order).
// Zero-kernel resets ticket/done each replay (ws not re-poisoned).

#define NROWS 1000000
#define DIM   128
#define NCLS  100
#define NSLICE 25
#define SROWS (NROWS / NSLICE)        // 40000 rows per slice
#define GPS   625                     // 64-row groups per slice
#define TPC   (GPS + NCLS)            // 725 tickets per slice-cycle
#define NTICKETS (NSLICE * TPC)       // 18125
#define PSTRIDE 132                   // 128 dims + count + pad (16B-aligned)
#define QCAP  128
#define QMASK 127

typedef __attribute__((ext_vector_type(4))) float f32x4;

// ---------------- zero control words (ticket + done[25]) ----------------
__global__ void l2cc_zero(int* __restrict__ ctrl)
{
    if (threadIdx.x < 32) ctrl[threadIdx.x] = 0;
}

// ---------------- p1: argmax for 16 rows (one wave pass, round-8 body) ----------------
__device__ __forceinline__ void argmax16(const float* __restrict__ logits,
                                         int* __restrict__ assign,
                                         int row_base, int qid, int p)
{
    const int row = row_base + qid;
    const float4* lrow = reinterpret_cast<const float4*>(logits + (size_t)row * NCLS);
    float best = -INFINITY;
    int   bi   = 0x7fffffff;
    #pragma unroll
    for (int i = 0; i < 6; ++i) {
        const float4 v = lrow[i * 4 + p];       // cols 16i+4p .. +3
        const int c0 = i * 16 + p * 4;
        if (v.x > best) { best = v.x; bi = c0;     }
        if (v.y > best) { best = v.y; bi = c0 + 1; }
        if (v.z > best) { best = v.z; bi = c0 + 2; }
        if (v.w > best) { best = v.w; bi = c0 + 3; }
    }
    {   // tail cols 96..99
        const float t = logits[(size_t)row * NCLS + 96 + p];
        if (t > best) { best = t; bi = 96 + p; }
    }
    #pragma unroll
    for (int off = 1; off <= 2; off <<= 1) {    // quad_perm DPP merge
        const float ov = __shfl_xor(best, off, 64);
        const int   oi = __shfl_xor(bi,   off, 64);
        if (ov > best || (ov == best && oi < bi)) { best = ov; bi = oi; }
    }
    if (p == 0) assign[row] = bi;
}

// ---------------- p2 helpers: per-wave queued batch-gather ----------------
#define DRAIN16                                                               \
    {                                                                         \
        _Pragma("unroll")                                                     \
        for (int k_ = 0; k_ < 8; ++k_) {                                      \
            const int r_ = q[wave][(qhead + 2 * k_ + half) & QMASK];          \
            acc += *reinterpret_cast<const f32x4*>(                           \
                emb + (size_t)r_ * DIM + l5 * 4);                             \
        }                                                                     \
        qhead += 16;                                                          \
    }

#define PUSH(AV, OFF)                                                         \
    {                                                                         \
        const unsigned long long m_ = __ballot((AV) == c);                    \
        if ((AV) == c) {                                                      \
            const int rank_ = __popcll(m_ & ((1ull << lane) - 1ull));         \
            q[wave][(qtail + rank_) & QMASK] = rw + (OFF) + lane;             \
        }                                                                     \
        const int pc_ = __popcll(m_);                                         \
        qtail += pc_; icnt += pc_;                                            \
        while (qtail - qhead >= 16) DRAIN16                                   \
    }

// ---------------- mega kernel: ticket loop over p1-groups and p2-gathers ----------------
__global__ __launch_bounds__(256, 5)
void l2cc_mega(const float* __restrict__ emb,
               const float* __restrict__ logits,
               int* __restrict__ ctrl,          // [0]=ticket, [1..25]=done
               int* __restrict__ assign,
               float* __restrict__ partial)
{
    __shared__ int q[4][QCAP];
    const int wave = threadIdx.x >> 6;
    const int lane = threadIdx.x & 63;
    const int qid  = lane >> 2;          // quad id (p1)
    const int p    = lane & 3;
    const int half = lane >> 5;          // (p2)
    const int l5   = lane & 31;

    int* tick = ctrl;
    int* done = ctrl + 1;

    for (;;) {
        int T;
        if (lane == 0) T = atomicAdd(tick, 1);
        T = __shfl(T, 0, 64);
        if (T >= NTICKETS) break;

        const int cyc = T / TPC;
        const int r   = T - cyc * TPC;

        if (r < GPS) {
            // ---------- p1: argmax one 64-row group ----------
            const int g = cyc * GPS + r;
            #pragma unroll
            for (int it = 0; it < 4; ++it)
                argmax16(logits, assign, g * 64 + it * 16, qid, p);
            __threadfence();                         // publish assign stores
            if (lane == 0) atomicAdd(&done[cyc], 1);
        } else {
            // ---------- p2: gather slice s for cluster c ----------
            const int s = cyc;
            const int c = r - GPS;
            while (__hip_atomic_load(&done[s], __ATOMIC_ACQUIRE,
                                     __HIP_MEMORY_SCOPE_AGENT) < GPS)
                __builtin_amdgcn_s_sleep(8);

            const int start = s * SROWS;
            const int end   = start + SROWS;

            f32x4 acc = {0.0f, 0.0f, 0.0f, 0.0f};
            int   icnt = 0, qhead = 0, qtail = 0;

            int rw = start;
            int a0 = (rw +   0 + lane < end) ? assign[rw +   0 + lane] : -1;
            int a1 = (rw +  64 + lane < end) ? assign[rw +  64 + lane] : -1;
            int a2 = (rw + 128 + lane < end) ? assign[rw + 128 + lane] : -1;
            int a3 = (rw + 192 + lane < end) ? assign[rw + 192 + lane] : -1;

            for (; rw < end; rw += 256) {
                const int rn = rw + 256;             // prefetch next 256-row window
                int b0 = -1, b1 = -1, b2 = -1, b3 = -1;
                if (rn < end) {
                    b0 = (rn +   0 + lane < end) ? assign[rn +   0 + lane] : -1;
                    b1 = (rn +  64 + lane < end) ? assign[rn +  64 + lane] : -1;
                    b2 = (rn + 128 + lane < end) ? assign[rn + 128 + lane] : -1;
                    b3 = (rn + 192 + lane < end) ? assign[rn + 192 + lane] : -1;
                }
                PUSH(a0, 0) PUSH(a1, 64) PUSH(a2, 128) PUSH(a3, 192)
                a0 = b0; a1 = b1; a2 = b2; a3 = b3;
            }
            // tail: remaining queued rows, lanes 0-31 only (cover all 128 dims)
            while (qtail > qhead) {
                const int rr = q[wave][qhead & QMASK]; ++qhead;
                if (half == 0)
                    acc += *reinterpret_cast<const f32x4*>(
                        emb + (size_t)rr * DIM + l5 * 4);
            }
            // combine halves (fixed expression, deterministic)
            f32x4 v;
            #pragma unroll
            for (int j = 0; j < 4; ++j)
                v[j] = acc[j] + __shfl_xor(acc[j], 32, 64);
            float* pp = partial + (size_t)(s * NCLS + c) * PSTRIDE;
            if (lane < 32)
                *reinterpret_cast<f32x4*>(pp + lane * 4) = v;  // dims 4l..4l+3
            if (lane == 0)
                pp[DIM] = (float)icnt;
        }
    }
}

// ---------------- K3: per-cluster slice reduction + distance epilogue ----------------
__global__ __launch_bounds__(128)
void l2cc_final(const float* __restrict__ partial,
                const float* __restrict__ centers,
                float* __restrict__ out)
{
    const int c = blockIdx.x;     // 0..99
    const int t = threadIdx.x;    // 0..127 = dim

    float s = 0.0f, cnt = 0.0f;
    #pragma unroll
    for (int sl = 0; sl < NSLICE; ++sl) {
        const float* p = partial + (size_t)(sl * NCLS + c) * PSTRIDE;
        s   += p[t];
        cnt += p[DIM];
    }

    const float centroid = s / fmaxf(cnt, 1.0f);
    const float dd = centers[c * DIM + t] - centroid;
    float sq = dd * dd;
    #pragma unroll
    for (int off = 32; off > 0; off >>= 1) sq += __shfl_xor(sq, off, 64);

    __shared__ float red[2];
    if ((t & 63) == 0) red[t >> 6] = sq;
    __syncthreads();
    if (t == 0) {
        const float total = red[0] + red[1];
        out[c] = (cnt > 0.0f && total > 0.0f) ? sqrtf(total) : 0.0f;
    }
}

extern "C" void kernel_launch(void* const* d_in, const int* in_sizes, int n_in,
                              void* d_out, int out_size, void* d_ws, size_t ws_size,
                              hipStream_t stream)
{
    const float* emb     = (const float*)d_in[0];  // [N, 128]
    const float* centers = (const float*)d_in[1];  // [100, 128]
    const float* logits  = (const float*)d_in[2];  // [N, 100]
    float* out = (float*)d_out;                    // [100]

    // ws layout: ctrl[32 ints] | assign[N ints] | partial[2500][132] f32
    int*   ctrl    = (int*)d_ws;
    int*   assign  = ctrl + 32;
    float* partial = (float*)((char*)d_ws + 128 + (size_t)NROWS * sizeof(int));

    l2cc_zero <<<1, 64, 0, stream>>>(ctrl);
    l2cc_mega <<<1280, 256, 0, stream>>>(emb, logits, ctrl, assign, partial);
    l2cc_final<<<NCLS, 128, 0, stream>>>(partial, centers, out);
}

// Round 16
// 527.411 us; speedup vs baseline: 4.4662x; 4.4662x over previous
//
#include <hip/hip_runtime.h>
#include <math.h>

// L2ClusterCentroid: N=1e6 rows, D=128, C=100.
// assign = argmax(logits, -1); centroids = segment_mean(embedding, assign);
// out[c] = counts[c]>0 ? ||centers[c] - centroids[c]||_2 : 0
//
// Round-16: r15's 13x regression = single-line ticket atomic (18125 blocking
// pulls x ~130ns serialized = 2.4ms). Keep the overlap thesis, remove ALL
// blocking sync: static roles (157 argmax blocks sweep slices in order;
// 1250 gather blocks own (slice, cluster-pair) statically). assign written
// with sc1 (agent-scope) stores / read with sc1 loads -> L3-coherent, no
// fences, no L2 invalidates. done[s] adds are relaxed + off-path
// (__syncthreads drains vmcnt first). Grid 1407 <= resident capacity 1536
// (launch_bounds(256,6)) -> spin-waits are deadlock-free.

#define NROWS 1000000
#define DIM   128
#define NCLS  100
#define NSLICE 25
#define SROWS (NROWS / NSLICE)        // 40000 rows per slice
#define GPS   625                     // 64-row groups per slice
#define GA    157                     // argmax blocks
#define GPB   4                       // groups per argmax block per slice
#define GB    1250                    // gather blocks (50 per slice x 2 clusters)
#define PSTRIDE 132                   // 128 dims + count + pad (16B-aligned)
#define QCAP  128
#define QMASK 127

typedef __attribute__((ext_vector_type(4))) float f32x4;

// ---------------- zero control words (done[25]) ----------------
__global__ void l2cc_zero(int* __restrict__ ctrl)
{
    if (threadIdx.x < 32) ctrl[threadIdx.x] = 0;
}

// ---------------- argmax of one 64-row group (round-8 proven body) ----------------
__device__ __forceinline__ void argmax_group(const float* __restrict__ logits,
                                             int* __restrict__ assign,
                                             int row_base, int qid, int p)
{
    const int row = row_base + qid;
    const float4* lrow = reinterpret_cast<const float4*>(logits + (size_t)row * NCLS);
    float best = -INFINITY;
    int   bi   = 0x7fffffff;
    #pragma unroll
    for (int i = 0; i < 6; ++i) {
        const float4 v = lrow[i * 4 + p];       // cols 16i+4p .. +3
        const int c0 = i * 16 + p * 4;
        if (v.x > best) { best = v.x; bi = c0;     }
        if (v.y > best) { best = v.y; bi = c0 + 1; }
        if (v.z > best) { best = v.z; bi = c0 + 2; }
        if (v.w > best) { best = v.w; bi = c0 + 3; }
    }
    {   // tail cols 96..99
        const float t = logits[(size_t)row * NCLS + 96 + p];
        if (t > best) { best = t; bi = 96 + p; }
    }
    #pragma unroll
    for (int off = 1; off <= 2; off <<= 1) {    // quad_perm DPP merge
        const float ov = __shfl_xor(best, off, 64);
        const int   oi = __shfl_xor(bi,   off, 64);
        if (ov > best || (ov == best && oi < bi)) { best = ov; bi = oi; }
    }
    if (p == 0)   // sc1 store: lands at L3 (coherence point), no fence needed
        __hip_atomic_store(&assign[row], bi, __ATOMIC_RELAXED,
                           __HIP_MEMORY_SCOPE_AGENT);
}

// ---------------- gather helpers: dual-cluster queued batch-gather ----------------
#define DRAINQ(QI, ACC, QH)                                                   \
    {                                                                         \
        _Pragma("unroll")                                                     \
        for (int k_ = 0; k_ < 8; ++k_) {                                      \
            const int r_ = q[wave][QI][((QH) + 2 * k_ + half) & QMASK];       \
            ACC += *reinterpret_cast<const f32x4*>(                           \
                emb + (size_t)r_ * DIM + l5 * 4);                             \
        }                                                                     \
        QH += 16;                                                             \
    }

#define PUSHC(AV, OFF, CC, QI, QT, QH, ACC, ICNT)                             \
    {                                                                         \
        const unsigned long long m_ = __ballot((AV) == (CC));                 \
        if ((AV) == (CC)) {                                                   \
            const int rank_ = __popcll(m_ & ((1ull << lane) - 1ull));         \
            q[wave][QI][((QT) + rank_) & QMASK] = rw + (OFF) + lane;          \
        }                                                                     \
        const int pc_ = __popcll(m_);                                         \
        QT += pc_; ICNT += pc_;                                               \
        while (QT - QH >= 16) DRAINQ(QI, ACC, QH)                             \
    }

#define PUSH2(AV, OFF)                                                        \
    PUSHC(AV, OFF, c0, 0, qt0, qh0, acc0, icnt0)                              \
    PUSHC(AV, OFF, c1, 1, qt1, qh1, acc1, icnt1)

#define ALOAD(IDX) (((IDX) < end)                                             \
    ? __hip_atomic_load(assign + (IDX), __ATOMIC_RELAXED,                     \
                        __HIP_MEMORY_SCOPE_AGENT)                             \
    : -1)

// ---------------- fused kernel: static argmax / gather roles ----------------
__global__ __launch_bounds__(256, 6)
void l2cc_mega(const float* __restrict__ emb,
               const float* __restrict__ logits,
               int* __restrict__ done,           // [25]
               int* __restrict__ assign,
               float* __restrict__ partial)
{
    const int tid = threadIdx.x;

    if (blockIdx.x < GA) {
        // ================= argmax role: sweep slices in order =================
        const int b   = blockIdx.x;
        const int qid = tid >> 2;     // row within 64-group
        const int p   = tid & 3;
        const int g0b = b * GPB;
        const int ng  = min(GPB, GPS - g0b);    // 4 (b<156) or 1 (b==156)

        for (int s = 0; s < NSLICE; ++s) {
            const int g0 = s * GPS + g0b;
            if (ng == GPB) {
                #pragma unroll
                for (int j = 0; j < GPB; ++j)
                    argmax_group(logits, assign, (g0 + j) * 64, qid, p);
            } else {
                for (int j = 0; j < ng; ++j)
                    argmax_group(logits, assign, (g0 + j) * 64, qid, p);
            }
            __syncthreads();   // drains each wave's vmcnt -> sc1 stores complete
            if (tid == 0)
                __hip_atomic_fetch_add(&done[s], 1, __ATOMIC_RELAXED,
                                       __HIP_MEMORY_SCOPE_AGENT);
        }
        return;
    }

    // ================= gather role: (slice, cluster-pair) static =================
    __shared__ int   q[4][2][QCAP];
    __shared__ f32x4 sacc[4][64];
    __shared__ int   scnt[4];

    const int gbid = blockIdx.x - GA;         // 0..1249
    const int s    = gbid / 50;               // slice 0..24
    const int k    = gbid - s * 50;           // cluster-pair 0..49
    const int c0   = 2 * k;
    const int c1   = c0 + 1;
    const int wave = tid >> 6;
    const int lane = tid & 63;
    const int half = lane >> 5;
    const int l5   = lane & 31;

    // wait for this slice's argmax (off-path for argmax; sleep-throttled)
    if (tid == 0) {
        while (__hip_atomic_load(&done[s], __ATOMIC_RELAXED,
                                 __HIP_MEMORY_SCOPE_AGENT) < GA)
            __builtin_amdgcn_s_sleep(64);
    }
    __syncthreads();

    const int start = s * SROWS;
    const int end   = start + SROWS;

    f32x4 acc0 = {0.f, 0.f, 0.f, 0.f}, acc1 = {0.f, 0.f, 0.f, 0.f};
    int icnt0 = 0, icnt1 = 0, qh0 = 0, qt0 = 0, qh1 = 0, qt1 = 0;

    int rw = start + wave * 256;
    int a0 = ALOAD(rw + 0 + lane);
    int a1 = ALOAD(rw + 64 + lane);
    int a2 = ALOAD(rw + 128 + lane);
    int a3 = ALOAD(rw + 192 + lane);

    for (; rw < end; rw += 1024) {
        const int rn = rw + 1024;             // prefetch next 256-row window
        int b0 = -1, b1 = -1, b2 = -1, b3 = -1;
        if (rn < end) {
            b0 = ALOAD(rn + 0 + lane);
            b1 = ALOAD(rn + 64 + lane);
            b2 = ALOAD(rn + 128 + lane);
            b3 = ALOAD(rn + 192 + lane);
        }
        PUSH2(a0, 0) PUSH2(a1, 64) PUSH2(a2, 128) PUSH2(a3, 192)
        a0 = b0; a1 = b1; a2 = b2; a3 = b3;
    }

    // tails: remaining queued rows, lanes 0-31 cover all 128 dims
    while (qt0 > qh0) {
        const int r = q[wave][0][qh0 & QMASK]; ++qh0;
        if (half == 0)
            acc0 += *reinterpret_cast<const f32x4*>(emb + (size_t)r * DIM + l5 * 4);
    }
    while (qt1 > qh1) {
        const int r = q[wave][1][qh1 & QMASK]; ++qh1;
        if (half == 0)
            acc1 += *reinterpret_cast<const f32x4*>(emb + (size_t)r * DIM + l5 * 4);
    }

    // cross-wave reduce + write, cluster c0 then c1 (fixed order, deterministic)
    sacc[wave][lane] = acc0;
    if (lane == 0) scnt[wave] = icnt0;
    __syncthreads();
    if (wave == 0 && lane < 32) {
        f32x4 v = (((sacc[0][lane] + sacc[1][lane]) + sacc[2][lane]) + sacc[3][lane])
                + (((sacc[0][32 + lane] + sacc[1][32 + lane])
                  + sacc[2][32 + lane]) + sacc[3][32 + lane]);
        float* pp = partial + (size_t)(s * NCLS + c0) * PSTRIDE;
        *reinterpret_cast<f32x4*>(pp + lane * 4) = v;
        if (lane == 0)
            pp[DIM] = (float)(((scnt[0] + scnt[1]) + scnt[2]) + scnt[3]);
    }
    __syncthreads();
    sacc[wave][lane] = acc1;
    if (lane == 0) scnt[wave] = icnt1;
    __syncthreads();
    if (wave == 0 && lane < 32) {
        f32x4 v = (((sacc[0][lane] + sacc[1][lane]) + sacc[2][lane]) + sacc[3][lane])
                + (((sacc[0][32 + lane] + sacc[1][32 + lane])
                  + sacc[2][32 + lane]) + sacc[3][32 + lane]);
        float* pp = partial + (size_t)(s * NCLS + c1) * PSTRIDE;
        *reinterpret_cast<f32x4*>(pp + lane * 4) = v;
        if (lane == 0)
            pp[DIM] = (float)(((scnt[0] + scnt[1]) + scnt[2]) + scnt[3]);
    }
}

// ---------------- K3: per-cluster slice reduction + distance epilogue ----------------
__global__ __launch_bounds__(128)
void l2cc_final(const float* __restrict__ partial,
                const float* __restrict__ centers,
                float* __restrict__ out)
{
    const int c = blockIdx.x;     // 0..99
    const int t = threadIdx.x;    // 0..127 = dim (linear layout)

    float s = 0.0f, cnt = 0.0f;
    #pragma unroll
    for (int sl = 0; sl < NSLICE; ++sl) {
        const float* p = partial + (size_t)(sl * NCLS + c) * PSTRIDE;
        s   += p[t];
        cnt += p[DIM];
    }

    const float centroid = s / fmaxf(cnt, 1.0f);
    const float dd = centers[c * DIM + t] - centroid;
    float sq = dd * dd;
    #pragma unroll
    for (int off = 32; off > 0; off >>= 1) sq += __shfl_xor(sq, off, 64);

    __shared__ float red[2];
    if ((t & 63) == 0) red[t >> 6] = sq;
    __syncthreads();
    if (t == 0) {
        const float total = red[0] + red[1];
        out[c] = (cnt > 0.0f && total > 0.0f) ? sqrtf(total) : 0.0f;
    }
}

extern "C" void kernel_launch(void* const* d_in, const int* in_sizes, int n_in,
                              void* d_out, int out_size, void* d_ws, size_t ws_size,
                              hipStream_t stream)
{
    const float* emb     = (const float*)d_in[0];  // [N, 128]
    const float* centers = (const float*)d_in[1];  // [100, 128]
    const float* logits  = (const float*)d_in[2];  // [N, 100]
    float* out = (float*)d_out;                    // [100]

    // ws layout: done[32 ints] | assign[N ints] | partial[2500][132] f32
    int*   ctrl    = (int*)d_ws;
    int*   assign  = ctrl + 32;
    float* partial = (float*)((char*)d_ws + 128 + (size_t)NROWS * sizeof(int));

    l2cc_zero <<<1, 64, 0, stream>>>(ctrl);
    l2cc_mega <<<GA + GB, 256, 0, stream>>>(emb, logits, ctrl, assign, partial);
    l2cc_final<<<NCLS, 128, 0, stream>>>(partial, centers, out);
}

// Round 17
// 183.829 us; speedup vs baseline: 12.8135x; 2.8690x over previous
//
#include <hip/hip_runtime.h>
#include <math.h>

// L2ClusterCentroid: N=1e6 rows, D=128, C=100.
// assign = argmax(logits, -1); centroids = segment_mean(embedding, assign);
// out[c] = counts[c]>0 ? ||centers[c] - centroids[c]||_2 : 0
//
// Round-17: RESTORE round-11 best (184us). Fusion experiments (r15 dynamic
// queue, r16 static roles) both regressed; K1 restructures (r9/r12/r13) all
// neutral-or-worse. This is the session-best configuration:
//  K1 argmax:  4 lanes/row, per-lane float4 scan, quad-DPP merge (~90us).
//  K2 gather:  per-(cluster,slice) block scan of cache-resident assign +
//              LDS match queue, 16-deep drains at 16B/lane (2 rows per
//              wave-instruction) (~85us).
//  K3 final:   fixed-order slice reduction + distance epilogue (~5us).

#define NROWS 1000000
#define DIM   128
#define NCLS  100
#define NSLICE 16
#define SLICE_ROWS (NROWS / NSLICE)   // 62500
#define PSTRIDE 132                   // 128 dims + count + pad (528 B, 16B-aligned)
#define QCAP  128
#define QMASK 127

typedef __attribute__((ext_vector_type(4))) float f32x4;

// ---------------- K1: argmax over logits rows (round-8 proven form) ----------------
__global__ __launch_bounds__(256)
void l2cc_argmax(const float* __restrict__ logits, int* __restrict__ assign)
{
    const int tid = threadIdx.x;
    const int row = blockIdx.x * 64 + (tid >> 2);
    const int p   = tid & 3;
    if (row >= NROWS) return;

    const float4* lrow = reinterpret_cast<const float4*>(logits + (size_t)row * NCLS);
    float best = -INFINITY;
    int   bi   = 0x7fffffff;
    #pragma unroll
    for (int i = 0; i < 6; ++i) {
        const float4 v = lrow[i * 4 + p];       // cols 16i+4p .. +3
        const int c0 = i * 16 + p * 4;
        if (v.x > best) { best = v.x; bi = c0;     }
        if (v.y > best) { best = v.y; bi = c0 + 1; }
        if (v.z > best) { best = v.z; bi = c0 + 2; }
        if (v.w > best) { best = v.w; bi = c0 + 3; }
    }
    {   // tail cols 96..99
        const float t = logits[(size_t)row * NCLS + 96 + p];
        if (t > best) { best = t; bi = 96 + p; }
    }
    #pragma unroll
    for (int off = 1; off <= 2; off <<= 1) {    // quad_perm DPP merge
        const float ov = __shfl_xor(best, off, 64);
        const int   oi = __shfl_xor(bi,   off, 64);
        if (ov > best || (ov == best && oi < bi)) { best = ov; bi = oi; }
    }
    if (p == 0) assign[row] = bi;
}

// ---------------- K2: scan + queued batch-gather (16B/lane drains) ----------------
// Drain 16 queued rows as 8 wave-instructions: lanes 0-31 take row 2k,
// lanes 32-63 take row 2k+1; each lane loads f32x4 = dims l5*4..+3.
#define DRAIN16                                                               \
    {                                                                         \
        _Pragma("unroll")                                                     \
        for (int k_ = 0; k_ < 8; ++k_) {                                      \
            const int r_ = q[wave][(qhead + 2 * k_ + half) & QMASK];          \
            acc += *reinterpret_cast<const f32x4*>(                           \
                emb + (size_t)r_ * DIM + l5 * 4);                             \
        }                                                                     \
        qhead += 16;                                                          \
    }

#define PUSH(AV, OFF)                                                         \
    {                                                                         \
        const unsigned long long m_ = __ballot((AV) == c);                    \
        if ((AV) == c) {                                                      \
            const int rank_ = __popcll(m_ & ((1ull << lane) - 1ull));         \
            q[wave][(qtail + rank_) & QMASK] = rw + (OFF) + lane;             \
        }                                                                     \
        const int pc_ = __popcll(m_);                                         \
        qtail += pc_; icnt += pc_;                                            \
        while (qtail - qhead >= 16) DRAIN16                                   \
    }

__global__ __launch_bounds__(256)
void l2cc_gather(const float* __restrict__ emb,
                 const int* __restrict__ assign,
                 float* __restrict__ partial)
{
    const int bid  = blockIdx.x;
    const int c    = bid / NSLICE;       // cluster this block owns
    const int sl   = bid - c * NSLICE;   // row-slice
    const int wave = threadIdx.x >> 6;
    const int lane = threadIdx.x & 63;
    const int half = lane >> 5;          // 0: even queue slot, 1: odd
    const int l5   = lane & 31;          // dim-quad index within row

    __shared__ int   q[4][QCAP];         // per-wave matched-row-id ring
    __shared__ f32x4 sacc[4][64];        // per-wave per-lane dim sums (4 KB)
    __shared__ int   scnt[4];

    const int start = sl * SLICE_ROWS;
    const int end   = start + SLICE_ROWS;

    f32x4 acc = {0.0f, 0.0f, 0.0f, 0.0f};
    int   icnt = 0, qhead = 0, qtail = 0;

    int rw = start + wave * 256;
    int a0 = (rw +   0 + lane < end) ? assign[rw +   0 + lane] : -1;
    int a1 = (rw +  64 + lane < end) ? assign[rw +  64 + lane] : -1;
    int a2 = (rw + 128 + lane < end) ? assign[rw + 128 + lane] : -1;
    int a3 = (rw + 192 + lane < end) ? assign[rw + 192 + lane] : -1;

    for (; rw < end; rw += 1024) {
        const int rn = rw + 1024;        // prefetch next 256-row group
        int b0 = -1, b1 = -1, b2 = -1, b3 = -1;
        if (rn < end) {
            b0 = (rn +   0 + lane < end) ? assign[rn +   0 + lane] : -1;
            b1 = (rn +  64 + lane < end) ? assign[rn +  64 + lane] : -1;
            b2 = (rn + 128 + lane < end) ? assign[rn + 128 + lane] : -1;
            b3 = (rn + 192 + lane < end) ? assign[rn + 192 + lane] : -1;
        }

        PUSH(a0, 0) PUSH(a1, 64) PUSH(a2, 128) PUSH(a3, 192)

        a0 = b0; a1 = b1; a2 = b2; a3 = b3;
    }

    // tail: remaining queued rows, one at a time (half-wave active)
    while (qtail > qhead) {
        const int r = q[wave][qhead & QMASK]; ++qhead;
        if (half == 0)
            acc += *reinterpret_cast<const f32x4*>(emb + (size_t)r * DIM + l5 * 4);
    }

    // cross-wave/half reduce (fixed order, deterministic)
    sacc[wave][lane] = acc;
    if (lane == 0) scnt[wave] = icnt;
    __syncthreads();
    if (wave == 0 && lane < 32) {
        f32x4 v = (((sacc[0][lane] + sacc[1][lane]) + sacc[2][lane]) + sacc[3][lane])
                + (((sacc[0][32 + lane] + sacc[1][32 + lane])
                  + sacc[2][32 + lane]) + sacc[3][32 + lane]);
        float* p = partial + (size_t)bid * PSTRIDE;
        *reinterpret_cast<f32x4*>(p + lane * 4) = v;       // dims 4l..4l+3 (linear)
        if (lane == 0)
            p[DIM] = (float)(((scnt[0] + scnt[1]) + scnt[2]) + scnt[3]);
    }
}

// ---------------- K3: per-cluster slice reduction + distance epilogue ----------------
__global__ __launch_bounds__(128)
void l2cc_final(const float* __restrict__ partial,
                const float* __restrict__ centers,
                float* __restrict__ out)
{
    const int c = blockIdx.x;     // 0..99
    const int t = threadIdx.x;    // 0..127 = dim (linear layout)

    float s = 0.0f, cnt = 0.0f;
    #pragma unroll
    for (int sl = 0; sl < NSLICE; ++sl) {
        const float* p = partial + (size_t)(c * NSLICE + sl) * PSTRIDE;
        s   += p[t];
        cnt += p[DIM];
    }

    const float centroid = s / fmaxf(cnt, 1.0f);
    const float dd = centers[c * DIM + t] - centroid;
    float sq = dd * dd;
    #pragma unroll
    for (int off = 32; off > 0; off >>= 1) sq += __shfl_xor(sq, off, 64);

    __shared__ float red[2];
    if ((t & 63) == 0) red[t >> 6] = sq;
    __syncthreads();
    if (t == 0) {
        const float total = red[0] + red[1];
        out[c] = (cnt > 0.0f && total > 0.0f) ? sqrtf(total) : 0.0f;
    }
}

extern "C" void kernel_launch(void* const* d_in, const int* in_sizes, int n_in,
                              void* d_out, int out_size, void* d_ws, size_t ws_size,
                              hipStream_t stream)
{
    const float* emb     = (const float*)d_in[0];  // [N, 128]
    const float* centers = (const float*)d_in[1];  // [100, 128]
    const float* logits  = (const float*)d_in[2];  // [N, 100]
    float* out = (float*)d_out;                    // [100]

    // workspace: assign [N ints, 4 MB] then partials [1600][132] f32 (~845 KB)
    int*   assign  = (int*)d_ws;
    float* partial = (float*)((char*)d_ws + (size_t)NROWS * sizeof(int));

    l2cc_argmax<<<(NROWS + 63) / 64, 256, 0, stream>>>(logits, assign);
    l2cc_gather<<<NCLS * NSLICE, 256, 0, stream>>>(emb, assign, partial);
    l2cc_final <<<NCLS, 128, 0, stream>>>(partial, centers, out);
}